// Round 1
// baseline (659.286 us; speedup 1.0000x reference)
//
#include <hip/hip_runtime.h>

#define M_OUT   125000
#define CIN     96
#define COUT    192
#define KOCT    8
#define MT      128      // rows per block
#define LDA     104      // padded bf16 stride (96 + 8), 208 B = 16B-aligned, 2-way-bank-free
#define LDB     104
#define BN_EPS  1e-5f

// ws layout (floats at base):
//   [0,192)   sums   [192,384) sumsq   [384,576) scale   [576,768) shift
// byte 4096: bf16 WT[k][n][c_pad104]  (8*192*104*2 = 319488 B)
#define WS_SCALE_OFF 384
#define WS_WT_BYTE   4096

typedef __attribute__((ext_vector_type(8))) short bf16x8;
typedef __attribute__((ext_vector_type(4))) float f32x4;

__device__ __forceinline__ unsigned short f2bf(float f) {
    unsigned int u = __float_as_uint(f);
    u += 0x7FFF + ((u >> 16) & 1);           // RNE
    return (unsigned short)(u >> 16);
}

__device__ __forceinline__ unsigned int pack2(float a, float b) {
    unsigned int ua = __float_as_uint(a);
    unsigned int ub = __float_as_uint(b);
    ua += 0x7FFF + ((ua >> 16) & 1);
    ub += 0x7FFF + ((ub >> 16) & 1);
    return (ua >> 16) | (ub & 0xFFFF0000u);
}

// ---------------- prep: zero stats + build bf16 transposed padded weights ----
__global__ void prep_kernel(const float* __restrict__ W, float* __restrict__ ws_f,
                            unsigned short* __restrict__ wt) {
    int gid = blockIdx.x * blockDim.x + threadIdx.x;
    if (gid < 384) ws_f[gid] = 0.0f;
    if (gid < KOCT * COUT * LDA) {
        int c = gid % LDA;
        int rest = gid / LDA;
        int n = rest % COUT;
        int k = rest / COUT;
        float v = (c < CIN) ? W[(k * CIN + c) * COUT + n] : 0.0f;
        wt[gid] = f2bf(v);
    }
}

// ---------------- conv: gather-GEMM with bf16 MFMA + stat reduction ----------
__global__ __launch_bounds__(256, 2)
void conv_kernel(const float* __restrict__ data,
                 const int* __restrict__ neigh,
                 const float* __restrict__ bias,
                 const unsigned short* __restrict__ wt,
                 float* __restrict__ out,
                 float* __restrict__ gsum) {
    __shared__ unsigned short As[MT * LDA];     // 26624 B
    __shared__ unsigned short Bs[COUT * LDB];   // 39936 B
    __shared__ int   idxs[MT * KOCT];           // 4096 B
    __shared__ float stats[2 * COUT];           // 1536 B

    const int t    = threadIdx.x;
    const int wave = t >> 6;
    const int lane = t & 63;
    const int quad = lane >> 4;
    const int l15  = lane & 15;
    const int wr   = wave >> 1;   // 0..1 : row half (64 rows)
    const int wc   = wave & 1;    // 0..1 : col half (96 cols)
    const int m0   = blockIdx.x * MT;

    // stage neighbor indices for all 8 octants + zero the stat buffer
    {
        int r  = t >> 1;              // 0..127
        int gm = m0 + r;
        int4 v;
        if (gm < M_OUT) {
            v = *reinterpret_cast<const int4*>(neigh + gm * 8 + (t & 1) * 4);
        } else {
            v.x = v.y = v.z = v.w = -1;
        }
        *reinterpret_cast<int4*>(idxs + t * 4) = v;
        for (int i = t; i < 2 * COUT; i += 256) stats[i] = 0.0f;
    }

    const f32x4 vzero = {0.f, 0.f, 0.f, 0.f};
    f32x4 acc[4][6];
#pragma unroll
    for (int i = 0; i < 4; ++i)
#pragma unroll
        for (int j = 0; j < 6; ++j) acc[i][j] = vzero;

    __syncthreads();

    for (int k = 0; k < KOCT; ++k) {
        // ---- stage A: gather 128 rows x 96 ch, fp32 -> bf16
#pragma unroll
        for (int j = 0; j < 12; ++j) {
            int lin = j * 256 + t;
            int row = lin / 24;
            int f4  = lin - row * 24;
            int idx = idxs[row * 8 + k];
            unsigned int lo = 0u, hi = 0u;
            if (idx >= 0) {
                float4 v = *reinterpret_cast<const float4*>(data + (size_t)idx * CIN + f4 * 4);
                lo = pack2(v.x, v.y);
                hi = pack2(v.z, v.w);
            }
            uint2 p; p.x = lo; p.y = hi;
            *reinterpret_cast<uint2*>(&As[row * LDA + f4 * 4]) = p;
        }
        // ---- stage B: copy WT[k] (192x104 bf16 = 2496 uint4) from ws (L2-hot)
        {
            const uint4* src = reinterpret_cast<const uint4*>(wt + k * COUT * LDB);
            uint4* dst = reinterpret_cast<uint4*>(Bs);
#pragma unroll
            for (int j = 0; j < 10; ++j) {
                int i = j * 256 + t;
                if (i < (COUT * LDB * 2) / 16) dst[i] = src[i];
            }
        }
        __syncthreads();

        // ---- 3 MFMA k-steps of 32 over this octant's 96 channels
#pragma unroll
        for (int ks = 0; ks < 3; ++ks) {
            bf16x8 af[4], bfr[6];
#pragma unroll
            for (int rt = 0; rt < 4; ++rt) {
                int row = wr * 64 + rt * 16 + l15;
                af[rt] = *reinterpret_cast<const bf16x8*>(&As[row * LDA + ks * 32 + quad * 8]);
            }
#pragma unroll
            for (int ct = 0; ct < 6; ++ct) {
                int n = wc * 96 + ct * 16 + l15;
                bfr[ct] = *reinterpret_cast<const bf16x8*>(&Bs[n * LDB + ks * 32 + quad * 8]);
            }
#pragma unroll
            for (int rt = 0; rt < 4; ++rt)
#pragma unroll
                for (int ct = 0; ct < 6; ++ct)
                    acc[rt][ct] = __builtin_amdgcn_mfma_f32_16x16x32_bf16(
                        af[rt], bfr[ct], acc[rt][ct], 0, 0, 0);
        }
        __syncthreads();
    }

    // ---- epilogue: + bias, store conv-out fp32, per-channel sum/sumsq
#pragma unroll
    for (int ct = 0; ct < 6; ++ct) {
        int col = wc * 96 + ct * 16 + l15;
        float b = bias[col];
        float s1 = 0.f, s2 = 0.f;
#pragma unroll
        for (int rt = 0; rt < 4; ++rt) {
#pragma unroll
            for (int r = 0; r < 4; ++r) {
                int gm = m0 + wr * 64 + rt * 16 + quad * 4 + r;
                if (gm < M_OUT) {
                    float v = acc[rt][ct][r] + b;
                    out[(size_t)gm * COUT + col] = v;
                    s1 += v;
                    s2 += v * v;
                }
            }
        }
        atomicAdd(&stats[col], s1);
        atomicAdd(&stats[COUT + col], s2);
    }
    __syncthreads();
    for (int i = t; i < COUT; i += 256) {
        atomicAdd(&gsum[i], stats[i]);
        atomicAdd(&gsum[COUT + i], stats[COUT + i]);
    }
}

// ---------------- finalize: per-channel scale/shift -------------------------
__global__ void finalize_kernel(const float* __restrict__ gsum,
                                const float* __restrict__ gamma,
                                const float* __restrict__ beta,
                                float* __restrict__ ss) {
    int c = threadIdx.x;
    if (c < COUT) {
        float inv_m = 1.0f / (float)M_OUT;
        float mean = gsum[c] * inv_m;
        float var  = gsum[COUT + c] * inv_m - mean * mean;
        float rstd = rsqrtf(var + BN_EPS);
        float sc   = gamma[c] * rstd;
        ss[c]        = sc;
        ss[COUT + c] = beta[c] - mean * sc;
    }
}

// ---------------- normalize: y = x*scale[c] + shift[c] ----------------------
__global__ void norm_kernel(float* __restrict__ out, const float* __restrict__ ss) {
    __shared__ float s_scale[COUT], s_shift[COUT];
    for (int i = threadIdx.x; i < COUT; i += blockDim.x) {
        s_scale[i] = ss[i];
        s_shift[i] = ss[COUT + i];
    }
    __syncthreads();
    const int total4 = M_OUT * COUT / 4;   // 6,000,000
    int stride = gridDim.x * blockDim.x;
    for (int i = blockIdx.x * blockDim.x + threadIdx.x; i < total4; i += stride) {
        float4 v = reinterpret_cast<float4*>(out)[i];
        int c4 = (i % (COUT / 4)) * 4;
        v.x = v.x * s_scale[c4 + 0] + s_shift[c4 + 0];
        v.y = v.y * s_scale[c4 + 1] + s_shift[c4 + 1];
        v.z = v.z * s_scale[c4 + 2] + s_shift[c4 + 2];
        v.w = v.w * s_scale[c4 + 3] + s_shift[c4 + 3];
        reinterpret_cast<float4*>(out)[i] = v;
    }
}

extern "C" void kernel_launch(void* const* d_in, const int* in_sizes, int n_in,
                              void* d_out, int out_size, void* d_ws, size_t ws_size,
                              hipStream_t stream) {
    const float* data  = (const float*)d_in[0];
    const float* W     = (const float*)d_in[1];
    const float* bias  = (const float*)d_in[2];
    const float* gamma = (const float*)d_in[3];
    const float* beta  = (const float*)d_in[4];
    const int*   neigh = (const int*)d_in[5];
    float* out  = (float*)d_out;
    float* ws_f = (float*)d_ws;
    unsigned short* wt = (unsigned short*)((char*)d_ws + WS_WT_BYTE);

    // 1. prep: zero stats, build bf16 weights (8*192*104 = 159744 elems)
    prep_kernel<<<(KOCT * COUT * LDA + 255) / 256, 256, 0, stream>>>(W, ws_f, wt);

    // 2. gather-GEMM conv + stat accumulation
    int grid1 = (M_OUT + MT - 1) / MT;   // 977
    conv_kernel<<<grid1, 256, 0, stream>>>(data, neigh, bias, wt, out, ws_f);

    // 3. per-channel scale/shift
    finalize_kernel<<<1, 192, 0, stream>>>(ws_f, gamma, beta, ws_f + WS_SCALE_OFF);

    // 4. in-place normalize
    norm_kernel<<<4096, 256, 0, stream>>>(out, ws_f + WS_SCALE_OFF);
}